// Round 4
// baseline (312.720 us; speedup 1.0000x reference)
//
#include <hip/hip_runtime.h>

// SNN: 2-layer LIF, T=4096, B=1024, 6->10->27.
// Round 4 = round 3 design with the writelane compile fix:
//   2 waves per block (block = one batch element):
//   wave 0: t-parallel cur1 precompute + sequential mem1 chain; gathers per-step
//           masks into one VGPR via predicated select (lane t = mask[t]); one
//           ds_write_b32 per chunk publishes them.
//   wave 1: consumes masks of chunk k-1 (readlane -> SGPR), 2 LDS table reads/step,
//           sequential mem2 chain.
// Chains run CONCURRENTLY on different SIMDs; 2 waves/SIMD hide each other's stalls.
// Arithmetic identical to rounds 1-2 (absmax 0.0): same fma order, cndmask reset,
// same table construction.

#define T_STEPS 4096
#define BETA 0.9f
#define THRESH 1.0f
#define CH 64
#define NCHUNK (T_STEPS / CH)
#define GRP 8
#define NGRP (CH / GRP)

__global__ __launch_bounds__(128, 1) void snn_kernel(
    const float* __restrict__ x,   // [B][6][T]
    const float* __restrict__ W1,  // [10][6]
    const float* __restrict__ b1,  // [10]
    const float* __restrict__ W2,  // [27][10]
    const float* __restrict__ b2,  // [27]
    float* __restrict__ out)       // [B][27]
{
    __shared__ float tabLo[32 * 32];     // [m][j]: b2[j] + sum_{i<5} bit_i(m)*W2[j][i]
    __shared__ float tabHi[32 * 32];     // [m][j]: sum_{i<5} bit_i(m)*W2[j][5+i]
    __shared__ float curBuf[10 * 68];    // wave-0 private transpose buffer
    __shared__ unsigned maskBuf[2][64];  // double-buffered spike masks, [chunk&1][t]

    const int tid = threadIdx.x;
    const int wid = tid >> 6;
    const int l   = tid & 63;
    const int b   = blockIdx.x;

    // ---- layer-2 lookup tables (identical construction to rounds 1-2) ----
    if (tid < 32) {
        for (int j = 0; j < 27; ++j) {
            float slo = b2[j];
            float shi = 0.0f;
            #pragma unroll
            for (int i = 0; i < 5; ++i) {
                if (tid & (1 << i)) {
                    slo += W2[j * 10 + i];
                    shi += W2[j * 10 + 5 + i];
                }
            }
            tabLo[tid * 32 + j] = slo;
            tabHi[tid * 32 + j] = shi;
        }
    }

    // ---- wave-0 state ----
    float w1r[60], b1r[10];
    float xv[6], xn[6];
    float mem1 = 0.0f;
    bool  sp1 = false;
    const int ri = (l < 10) ? l : 9;
    const float* cp = &curBuf[ri * 68];
    const float* xb = x + (size_t)b * 6 * T_STEPS;

    if (wid == 0) {
        #pragma unroll
        for (int i = 0; i < 10; ++i) {
            b1r[i] = b1[i];
            #pragma unroll
            for (int c = 0; c < 6; ++c) w1r[i * 6 + c] = W1[i * 6 + c];
        }
        #pragma unroll
        for (int c = 0; c < 6; ++c) xv[c] = xb[c * T_STEPS + l];
    }

    // ---- wave-1 state ----
    float mem2 = 0.0f;
    bool  sp2 = false;
    const int rj = (l < 27) ? l : 26;

    __syncthreads();

    #pragma unroll 1
    for (int k = 0; k <= NCHUNK; ++k) {
        // ================= wave 0: layer 1, chunk k =================
        if (wid == 0 && k < NCHUNK) {
            // t-parallel cur1 (lane = timestep), same fma order as before
            #pragma unroll
            for (int i = 0; i < 10; ++i) {
                float acc = xv[0] * w1r[i * 6 + 0];
                acc = fmaf(xv[1], w1r[i * 6 + 1], acc);
                acc = fmaf(xv[2], w1r[i * 6 + 2], acc);
                acc = fmaf(xv[3], w1r[i * 6 + 3], acc);
                acc = fmaf(xv[4], w1r[i * 6 + 4], acc);
                acc = fmaf(xv[5], w1r[i * 6 + 5], acc);
                curBuf[i * 68 + l] = acc + b1r[i];
            }
            // prefetch next chunk's x (no vmcnt drain anywhere near)
            if (k + 1 < NCHUNK) {
                #pragma unroll
                for (int c = 0; c < 6; ++c) xn[c] = xb[c * T_STEPS + (k + 1) * CH + l];
            }

            unsigned vmask = 0u;   // lane t accumulates mask[t] via predicated select
            float c1v[8];
            {
                float4 q0 = *(const float4*)(cp + 0);
                float4 q1 = *(const float4*)(cp + 4);
                c1v[0] = q0.x; c1v[1] = q0.y; c1v[2] = q0.z; c1v[3] = q0.w;
                c1v[4] = q1.x; c1v[5] = q1.y; c1v[6] = q1.z; c1v[7] = q1.w;
            }
            #pragma unroll
            for (int g = 0; g < NGRP; ++g) {
                float c1n[8];
                if (g + 1 < NGRP) {   // prefetch next group's currents
                    float4 p0 = *(const float4*)(cp + (g + 1) * 8);
                    float4 p1 = *(const float4*)(cp + (g + 1) * 8 + 4);
                    c1n[0] = p0.x; c1n[1] = p0.y; c1n[2] = p0.z; c1n[3] = p0.w;
                    c1n[4] = p1.x; c1n[5] = p1.y; c1n[6] = p1.z; c1n[7] = p1.w;
                }
                #pragma unroll
                for (int s = 0; s < 8; ++s) {
                    float t1 = fmaf(BETA, mem1, c1v[s]);
                    mem1 = sp1 ? (t1 - THRESH) : t1;       // == t1 - rst*THRESH
                    sp1 = mem1 > THRESH;
                    unsigned m = (unsigned)__ballot(sp1);  // wave-uniform (SGPR)
                    vmask = (l == g * 8 + s) ? m : vmask;  // v_cmp + v_cndmask
                }
                if (g + 1 < NGRP) {
                    #pragma unroll
                    for (int s = 0; s < 8; ++s) c1v[s] = c1n[s];
                }
            }
            maskBuf[k & 1][l] = vmask;   // one ds_write_b32: lane t publishes mask[t]
        }

        // ================= wave 1: layer 2, chunk k-1 =================
        if (wid == 1 && k >= 1) {
            unsigned vmask = maskBuf[(k - 1) & 1][l];   // lane t = mask[t]

            unsigned mlo[GRP], mhi[GRP];   // wave-uniform pre-scaled row offsets (SGPR)
            float tlo[GRP], thi[GRP];
            #pragma unroll
            for (int s = 0; s < 8; ++s) {
                unsigned m = (unsigned)__builtin_amdgcn_readlane((int)vmask, s);
                mlo[s] = (m & 31u) << 5;
                mhi[s] = ((m >> 5) & 31u) << 5;
            }
            #pragma unroll
            for (int s = 0; s < 8; ++s) {
                tlo[s] = tabLo[mlo[s] + rj];
                thi[s] = tabHi[mhi[s] + rj];
            }

            #pragma unroll
            for (int g = 0; g < NGRP; ++g) {
                unsigned nlo[GRP], nhi[GRP];
                float ntl[GRP], nth[GRP];
                if (g + 1 < NGRP) {   // next group's readlanes + table reads in flight
                    #pragma unroll
                    for (int s = 0; s < 8; ++s) {
                        unsigned m = (unsigned)__builtin_amdgcn_readlane(
                            (int)vmask, (g + 1) * 8 + s);
                        nlo[s] = (m & 31u) << 5;
                        nhi[s] = ((m >> 5) & 31u) << 5;
                    }
                    #pragma unroll
                    for (int s = 0; s < 8; ++s) {
                        ntl[s] = tabLo[nlo[s] + rj];
                        nth[s] = tabHi[nhi[s] + rj];
                    }
                }
                #pragma unroll
                for (int s = 0; s < 8; ++s) {
                    float cur2 = tlo[s] + thi[s];          // b2 folded into tabLo
                    float t2 = fmaf(BETA, mem2, cur2);
                    mem2 = sp2 ? (t2 - THRESH) : t2;
                    sp2 = mem2 > THRESH;
                }
                if (g + 1 < NGRP) {
                    #pragma unroll
                    for (int s = 0; s < 8; ++s) { tlo[s] = ntl[s]; thi[s] = nth[s]; }
                }
            }
        }

        if (wid == 0 && k + 1 < NCHUNK) {
            #pragma unroll
            for (int c = 0; c < 6; ++c) xv[c] = xn[c];
        }

        __syncthreads();   // uniform: both waves hit this every iteration
    }

    if (wid == 1 && l < 27) {
        out[b * 27 + l] = sp2 ? 1.0f : 0.0f;
    }
}

extern "C" void kernel_launch(void* const* d_in, const int* in_sizes, int n_in,
                              void* d_out, int out_size, void* d_ws, size_t ws_size,
                              hipStream_t stream) {
    const float* x  = (const float*)d_in[0];
    const float* W1 = (const float*)d_in[1];
    const float* b1 = (const float*)d_in[2];
    const float* W2 = (const float*)d_in[3];
    const float* b2 = (const float*)d_in[4];
    float* out = (float*)d_out;

    const int B = in_sizes[0] / (6 * T_STEPS);  // 1024
    snn_kernel<<<dim3(B), dim3(128), 0, stream>>>(x, W1, b1, W2, b2, out);
}

// Round 5
// 302.318 us; speedup vs baseline: 1.0344x; 1.0344x over previous
//
#include <hip/hip_runtime.h>

// SNN: 2-layer LIF, T=4096, B=1024, 6->10->27.
// Round 5: 3-wave, lag-2 pipeline per block (block = one batch element):
//   wave 0: t-parallel cur1 + sequential mem1 chain -> publishes masks[k] (1 ds_write)
//   wave G: STEP-PARALLEL table gather for chunk k-1: lane=(half h, neuron j);
//           per round r, gathers tabLo/tabHi rows for steps 2r+h at per-lane
//           addresses (no readlane, no serial deps) -> cur2Buf[k-1]
//   wave 2: pure mem2 recurrence on prepared cur2 (chunk k-2): b128 + fma/cndmask/cmp
// Arithmetic identical to rounds 1-4 (absmax 0.0): same add/fma order, cndmask reset,
// same table construction.

#define T_STEPS 4096
#define BETA 0.9f
#define THRESH 1.0f
#define CH 64
#define NCHUNK (T_STEPS / CH)   // 64
#define GRP 8
#define NGRP (CH / GRP)

__global__ __launch_bounds__(192, 1) void snn_kernel(
    const float* __restrict__ x,   // [B][6][T]
    const float* __restrict__ W1,  // [10][6]
    const float* __restrict__ b1,  // [10]
    const float* __restrict__ W2,  // [27][10]
    const float* __restrict__ b2,  // [27]
    float* __restrict__ out)       // [B][27]
{
    __shared__ float tabLo[32 * 32];      // [m][j]: b2[j] + sum_{i<5} bit_i(m)*W2[j][i]
    __shared__ float tabHi[32 * 32];      // [m][j]: sum_{i<5} bit_i(m)*W2[j][5+i]
    __shared__ float curBuf[10 * 68];     // wave-0 private
    __shared__ unsigned maskBuf[2][64];   // [parity][t]
    __shared__ float cur2Buf[2][27 * 68]; // [parity][neuron][t]

    const int tid = threadIdx.x;
    const int wid = tid >> 6;
    const int l   = tid & 63;
    const int b   = blockIdx.x;

    // ---- layer-2 lookup tables (identical construction to rounds 1-4) ----
    if (tid < 32) {
        for (int j = 0; j < 27; ++j) {
            float slo = b2[j];
            float shi = 0.0f;
            #pragma unroll
            for (int i = 0; i < 5; ++i) {
                if (tid & (1 << i)) {
                    slo += W2[j * 10 + i];
                    shi += W2[j * 10 + 5 + i];
                }
            }
            tabLo[tid * 32 + j] = slo;
            tabHi[tid * 32 + j] = shi;
        }
    }

    // ---- wave-0 state ----
    float w1r[60], b1r[10];
    float xv[6], xn[6];
    float mem1 = 0.0f;
    bool  sp1 = false;
    const int ri = (l < 10) ? l : 9;
    const float* cp = &curBuf[ri * 68];
    const float* xb = x + (size_t)b * 6 * T_STEPS;

    if (wid == 0) {
        #pragma unroll
        for (int i = 0; i < 10; ++i) {
            b1r[i] = b1[i];
            #pragma unroll
            for (int c = 0; c < 6; ++c) w1r[i * 6 + c] = W1[i * 6 + c];
        }
        #pragma unroll
        for (int c = 0; c < 6; ++c) xv[c] = xb[c * T_STEPS + l];
    }

    // ---- wave-G state: lane = (h = step half, j = neuron) ----
    const int gh = l >> 5;                        // 0 or 1
    const int gjr = l & 31;
    const int gj = (gjr < 27) ? gjr : 26;         // clamp: dup lanes write same value

    // ---- wave-2 state ----
    float mem2 = 0.0f;
    bool  sp2 = false;
    const int rj = (l < 27) ? l : 26;

    __syncthreads();

    #pragma unroll 1
    for (int k = 0; k <= NCHUNK + 1; ++k) {
        // ================= wave 0: layer 1, chunk k =================
        if (wid == 0 && k < NCHUNK) {
            #pragma unroll
            for (int i = 0; i < 10; ++i) {
                float acc = xv[0] * w1r[i * 6 + 0];
                acc = fmaf(xv[1], w1r[i * 6 + 1], acc);
                acc = fmaf(xv[2], w1r[i * 6 + 2], acc);
                acc = fmaf(xv[3], w1r[i * 6 + 3], acc);
                acc = fmaf(xv[4], w1r[i * 6 + 4], acc);
                acc = fmaf(xv[5], w1r[i * 6 + 5], acc);
                curBuf[i * 68 + l] = acc + b1r[i];
            }
            if (k + 1 < NCHUNK) {
                #pragma unroll
                for (int c = 0; c < 6; ++c) xn[c] = xb[c * T_STEPS + (k + 1) * CH + l];
            }

            unsigned vmask = 0u;   // lane t accumulates mask[t]
            float c1v[8];
            {
                float4 q0 = *(const float4*)(cp + 0);
                float4 q1 = *(const float4*)(cp + 4);
                c1v[0] = q0.x; c1v[1] = q0.y; c1v[2] = q0.z; c1v[3] = q0.w;
                c1v[4] = q1.x; c1v[5] = q1.y; c1v[6] = q1.z; c1v[7] = q1.w;
            }
            #pragma unroll
            for (int g = 0; g < NGRP; ++g) {
                float c1n[8];
                if (g + 1 < NGRP) {
                    float4 p0 = *(const float4*)(cp + (g + 1) * 8);
                    float4 p1 = *(const float4*)(cp + (g + 1) * 8 + 4);
                    c1n[0] = p0.x; c1n[1] = p0.y; c1n[2] = p0.z; c1n[3] = p0.w;
                    c1n[4] = p1.x; c1n[5] = p1.y; c1n[6] = p1.z; c1n[7] = p1.w;
                }
                #pragma unroll
                for (int s = 0; s < 8; ++s) {
                    float t1 = fmaf(BETA, mem1, c1v[s]);
                    mem1 = sp1 ? (t1 - THRESH) : t1;       // == t1 - rst*THRESH
                    sp1 = mem1 > THRESH;
                    unsigned m = (unsigned)__ballot(sp1);
                    vmask = (l == g * 8 + s) ? m : vmask;
                }
                if (g + 1 < NGRP) {
                    #pragma unroll
                    for (int s = 0; s < 8; ++s) c1v[s] = c1n[s];
                }
            }
            maskBuf[k & 1][l] = vmask;

            if (k + 1 < NCHUNK) {
                #pragma unroll
                for (int c = 0; c < 6; ++c) xv[c] = xn[c];
            }
        }

        // ============ wave G: step-parallel gather, chunk k-1 ============
        if (wid == 1 && k >= 1 && k <= NCHUNK) {
            const int par = (k - 1) & 1;
            const unsigned* mrow = &maskBuf[par][gh];       // + 2r per round
            float* crow = &cur2Buf[par][gj * 68 + gh];      // + 2r per round

            unsigned mr[32];
            #pragma unroll
            for (int r = 0; r < 32; ++r) mr[r] = mrow[2 * r];   // masks of steps 2r+gh
            #pragma unroll
            for (int r = 0; r < 32; ++r) {
                unsigned alo = (mr[r] & 31u) << 5;
                unsigned ahi = ((mr[r] >> 5) & 31u) << 5;
                crow[2 * r] = tabLo[alo + gj] + tabHi[ahi + gj];  // cur2 incl. b2
            }
        }

        // ============ wave 2: mem2 chain on chunk k-2 ============
        if (wid == 2 && k >= 2) {
            const float* cp2 = &cur2Buf[(k - 2) & 1][rj * 68];
            float c2v[8];
            {
                float4 q0 = *(const float4*)(cp2 + 0);
                float4 q1 = *(const float4*)(cp2 + 4);
                c2v[0] = q0.x; c2v[1] = q0.y; c2v[2] = q0.z; c2v[3] = q0.w;
                c2v[4] = q1.x; c2v[5] = q1.y; c2v[6] = q1.z; c2v[7] = q1.w;
            }
            #pragma unroll
            for (int g = 0; g < NGRP; ++g) {
                float c2n[8];
                if (g + 1 < NGRP) {
                    float4 p0 = *(const float4*)(cp2 + (g + 1) * 8);
                    float4 p1 = *(const float4*)(cp2 + (g + 1) * 8 + 4);
                    c2n[0] = p0.x; c2n[1] = p0.y; c2n[2] = p0.z; c2n[3] = p0.w;
                    c2n[4] = p1.x; c2n[5] = p1.y; c2n[6] = p1.z; c2n[7] = p1.w;
                }
                #pragma unroll
                for (int s = 0; s < 8; ++s) {
                    float t2 = fmaf(BETA, mem2, c2v[s]);
                    mem2 = sp2 ? (t2 - THRESH) : t2;
                    sp2 = mem2 > THRESH;
                }
                if (g + 1 < NGRP) {
                    #pragma unroll
                    for (int s = 0; s < 8; ++s) c2v[s] = c2n[s];
                }
            }
        }

        __syncthreads();   // uniform: all 3 waves, every iteration
    }

    if (wid == 2 && l < 27) {
        out[b * 27 + l] = sp2 ? 1.0f : 0.0f;
    }
}

extern "C" void kernel_launch(void* const* d_in, const int* in_sizes, int n_in,
                              void* d_out, int out_size, void* d_ws, size_t ws_size,
                              hipStream_t stream) {
    const float* x  = (const float*)d_in[0];
    const float* W1 = (const float*)d_in[1];
    const float* b1 = (const float*)d_in[2];
    const float* W2 = (const float*)d_in[3];
    const float* b2 = (const float*)d_in[4];
    float* out = (float*)d_out;

    const int B = in_sizes[0] / (6 * T_STEPS);  // 1024
    snn_kernel<<<dim3(B), dim3(192), 0, stream>>>(x, W1, b1, W2, b2, out);
}